// Round 2
// baseline (2185.409 us; speedup 1.0000x reference)
//
#include <hip/hip_runtime.h>
#include <hip/hip_bf16.h>
#include <math.h>

#define DD 1024
#define HSZ 128
#define NB 4
#define TT 2048
#define RPB 8

// ---------------- Kernel 1: QKV projection + RoPE (fp32) ----------------
// grid = B*T/RPB blocks, 256 threads.
// Outputs: q [B,2,T,HS], k [B,T,HS], v [B,T,HS] (fp32)
__global__ __launch_bounds__(256) void qkv_rope_kernel(
    const float* __restrict__ x,
    const float* __restrict__ Wq,
    const float* __restrict__ Wk,
    const float* __restrict__ Wv,
    float* __restrict__ qo,
    float* __restrict__ ko,
    float* __restrict__ vo)
{
    int row0 = blockIdx.x * RPB;    // b*T + t base (rows within one b: T%RPB==0)
    int tid = threadIdx.x;

    __shared__ float4 xs[RPB * 256];   // 8 rows x 1024 floats = 32 KB

    // stage 8 x-rows
    for (int i = tid; i < RPB * 256; i += 256) {
        int r = i >> 8, c = i & 255;
        xs[i] = ((const float4*)(x + (size_t)(row0 + r) * DD))[c];
    }
    __syncthreads();

    // 512 outputs per row: [0,256)=q (h*128+hs), [256,384)=k, [384,512)=v
    // thread handles out slot0 = tid (q) and slot1 = 256+tid (k/v)
    const float4* w0 = (const float4*)(Wq + (size_t)tid * DD);
    const float4* w1 = (tid < 128)
        ? (const float4*)(Wk + (size_t)tid * DD)
        : (const float4*)(Wv + (size_t)(tid - 128) * DD);

    float acc0[RPB], acc1[RPB];
    #pragma unroll
    for (int r = 0; r < RPB; ++r) { acc0[r] = 0.f; acc1[r] = 0.f; }

    for (int c = 0; c < 256; ++c) {
        float4 a = w0[c];
        float4 b = w1[c];
        #pragma unroll
        for (int r = 0; r < RPB; ++r) {
            float4 xv = xs[r * 256 + c];
            acc0[r] += xv.x * a.x + xv.y * a.y + xv.z * a.z + xv.w * a.w;
            acc1[r] += xv.x * b.x + xv.y * b.y + xv.z * b.z + xv.w * b.w;
        }
    }
    __syncthreads();   // done reading xs; reuse as outs

    float* outs = (float*)xs;         // [RPB][512]
    #pragma unroll
    for (int r = 0; r < RPB; ++r) {
        outs[r * 512 + tid] = acc0[r];
        outs[r * 512 + 256 + tid] = acc1[r];
    }
    __syncthreads();

    // RoPE: per row, 192 pair tasks (q: 2 heads x 64 pairs, k: 64 pairs)
    for (int i = tid; i < RPB * 192; i += 256) {
        int r = i / 192, j = i - r * 192;
        int t = (row0 + r) & (TT - 1);
        int base, pj;
        if (j < 128) { base = (j >> 6) * 128; pj = j & 63; }
        else         { base = 256;            pj = j - 128; }
        double th = pow(10000.0, -(double)pj / 32.0);
        double ang = (double)t * th;
        float c = (float)cos(ang), s = (float)sin(ang);
        float* o = outs + r * 512 + base + 2 * pj;
        float x0 = o[0], x1 = o[1];
        o[0] = x0 * c - x1 * s;
        o[1] = x1 * c + x0 * s;
    }
    __syncthreads();

    // write out
    int h = tid >> 7, hs = tid & 127;
    for (int r = 0; r < RPB; ++r) {
        int row = row0 + r;
        int t = row & (TT - 1), b = row >> 11;
        float* o = outs + r * 512;
        qo[(((size_t)b * 2 + h) * TT + t) * HSZ + hs] = o[tid];
        if (tid < 128) ko[(size_t)row * HSZ + tid] = o[256 + tid];
        else           vo[(size_t)row * HSZ + (tid - 128)] = o[256 + tid];
    }
}

// ---------------- Kernel 2: causal attention, one block per (b,t), both heads ----------------
// att output layout: [B,T,2,HS] fp32
__global__ __launch_bounds__(256) void attn_kernel(
    const float* __restrict__ q,
    const float* __restrict__ k,
    const float* __restrict__ v,
    float* __restrict__ att)
{
    int gid = blockIdx.x;            // b*T + t
    int t = gid & (TT - 1), b = gid >> 11;
    int tid = threadIdx.x;

    __shared__ float qs[2 * HSZ];
    __shared__ float ps[2][TT];
    __shared__ float red[2][4];
    __shared__ float4 pacc[256];

    // load q for both heads: tid<128 -> head0 elem tid, else head1
    {
        int hh = tid >> 7, dd = tid & 127;
        qs[tid] = q[(((size_t)b * 2 + hh) * TT + t) * HSZ + dd];
    }
    __syncthreads();

    const int L = t + 1;
    const float4* kb = (const float4*)(k + (size_t)b * TT * HSZ);
    const float scale = 0.08838834764831845f;   // 1/sqrt(128)

    // pass 1: scores + max
    float m0 = -1e30f, m1 = -1e30f;
    for (int s = tid; s < L; s += 256) {
        const float4* kr = kb + (size_t)s * 32;
        float a0 = 0.f, a1 = 0.f;
        #pragma unroll
        for (int c = 0; c < 32; ++c) {
            float4 kk = kr[c];
            float4 q0 = ((const float4*)qs)[c];
            float4 q1 = ((const float4*)qs)[32 + c];
            a0 += kk.x * q0.x + kk.y * q0.y + kk.z * q0.z + kk.w * q0.w;
            a1 += kk.x * q1.x + kk.y * q1.y + kk.z * q1.z + kk.w * q1.w;
        }
        a0 *= scale; a1 *= scale;
        ps[0][s] = a0; ps[1][s] = a1;
        m0 = fmaxf(m0, a0); m1 = fmaxf(m1, a1);
    }
    #pragma unroll
    for (int off = 32; off > 0; off >>= 1) {
        m0 = fmaxf(m0, __shfl_down(m0, off, 64));
        m1 = fmaxf(m1, __shfl_down(m1, off, 64));
    }
    if ((tid & 63) == 0) { red[0][tid >> 6] = m0; red[1][tid >> 6] = m1; }
    __syncthreads();
    float m0f = fmaxf(fmaxf(red[0][0], red[0][1]), fmaxf(red[0][2], red[0][3]));
    float m1f = fmaxf(fmaxf(red[1][0], red[1][1]), fmaxf(red[1][2], red[1][3]));
    __syncthreads();

    // pass 2: exp + sum
    float s0 = 0.f, s1 = 0.f;
    for (int s = tid; s < L; s += 256) {
        float e0 = __expf(ps[0][s] - m0f); ps[0][s] = e0; s0 += e0;
        float e1 = __expf(ps[1][s] - m1f); ps[1][s] = e1; s1 += e1;
    }
    #pragma unroll
    for (int off = 32; off > 0; off >>= 1) {
        s0 += __shfl_down(s0, off, 64);
        s1 += __shfl_down(s1, off, 64);
    }
    if ((tid & 63) == 0) { red[0][tid >> 6] = s0; red[1][tid >> 6] = s1; }
    __syncthreads();
    float inv0 = 1.f / (red[0][0] + red[0][1] + red[0][2] + red[0][3]);
    float inv1 = 1.f / (red[1][0] + red[1][1] + red[1][2] + red[1][3]);

    // PV: thread = (h, sgroup, 4dims). h=tid>>7, sg=(tid>>5)&3, d32=tid&31
    int h = tid >> 7, sg = (tid >> 5) & 3, d32 = tid & 31;
    const float4* vb = (const float4*)(v + (size_t)b * TT * HSZ);
    float4 acc = {0.f, 0.f, 0.f, 0.f};
    for (int s = sg; s < L; s += 4) {
        float w = ps[h][s];
        float4 vv = vb[(size_t)s * 32 + d32];
        acc.x += w * vv.x; acc.y += w * vv.y; acc.z += w * vv.z; acc.w += w * vv.w;
    }
    pacc[tid] = acc;
    __syncthreads();
    if (sg == 0) {
        float4 r0 = pacc[tid];
        float4 r1 = pacc[tid + 32];
        float4 r2 = pacc[tid + 64];
        float4 r3 = pacc[tid + 96];
        float inv = h ? inv1 : inv0;
        float4 r;
        r.x = (r0.x + r1.x + r2.x + r3.x) * inv;
        r.y = (r0.y + r1.y + r2.y + r3.y) * inv;
        r.z = (r0.z + r1.z + r2.z + r3.z) * inv;
        r.w = (r0.w + r1.w + r2.w + r3.w) * inv;
        ((float4*)att)[(((size_t)b * TT + t) * 2 + h) * 32 + d32] = r;
    }
}

// ---------------- Kernel 3: output projection (fp32) ----------------
// y[row, od] = sum_j att[row, j] * Wo[od, j], j in [0,256)
__global__ __launch_bounds__(256) void outproj_kernel(
    const float* __restrict__ att,
    const float* __restrict__ Wo,
    float* __restrict__ y)
{
    int row0 = blockIdx.x * RPB;
    int tid = threadIdx.x;

    __shared__ float4 as[RPB * 64];   // 8 rows x 256 floats = 8 KB
    for (int i = tid; i < RPB * 64; i += 256)
        as[i] = ((const float4*)att)[(size_t)row0 * 64 + i];
    __syncthreads();

    #pragma unroll
    for (int oo = 0; oo < 4; ++oo) {
        int od = tid + (oo << 8);
        const float4* wr = (const float4*)(Wo + (size_t)od * 256);
        float acc[RPB];
        #pragma unroll
        for (int r = 0; r < RPB; ++r) acc[r] = 0.f;
        for (int c = 0; c < 64; ++c) {
            float4 w4 = wr[c];
            #pragma unroll
            for (int r = 0; r < RPB; ++r) {
                float4 a4 = as[r * 64 + c];
                acc[r] += a4.x * w4.x + a4.y * w4.y + a4.z * w4.z + a4.w * w4.w;
            }
        }
        #pragma unroll
        for (int r = 0; r < RPB; ++r)
            y[(size_t)(row0 + r) * DD + od] = acc[r];
    }
}

extern "C" void kernel_launch(void* const* d_in, const int* in_sizes, int n_in,
                              void* d_out, int out_size, void* d_ws, size_t ws_size,
                              hipStream_t stream) {
    const float* x  = (const float*)d_in[0];
    const float* Wq = (const float*)d_in[1];
    const float* Wk = (const float*)d_in[2];
    const float* Wv = (const float*)d_in[3];
    const float* Wo = (const float*)d_in[4];
    float* y = (float*)d_out;

    // workspace layout (fp32): q 8MB | k 4MB | v 4MB | att 8MB = 24 MB
    char* ws = (char*)d_ws;
    float* qo = (float*)(ws);
    float* ko = (float*)(ws + 8u * 1024 * 1024);
    float* vo = (float*)(ws + 12u * 1024 * 1024);
    float* at = (float*)(ws + 16u * 1024 * 1024);

    const int rows = NB * TT;   // 8192
    qkv_rope_kernel<<<rows / RPB, 256, 0, stream>>>(x, Wq, Wk, Wv, qo, ko, vo);
    attn_kernel<<<rows, 256, 0, stream>>>(qo, ko, vo, at);
    outproj_kernel<<<rows / RPB, 256, 0, stream>>>(at, Wo, y);
}

// Round 3
// 783.005 us; speedup vs baseline: 2.7911x; 2.7911x over previous
//
#include <hip/hip_runtime.h>
#include <math.h>

#define DD 1024
#define HSZ 128
#define NB 4
#define TT 2048
#define RPB 8

typedef __attribute__((ext_vector_type(8))) short bf16x8;
typedef __attribute__((ext_vector_type(4))) float f32x4;

__device__ inline unsigned short f2bf(float f){
    unsigned u = __builtin_bit_cast(unsigned, f);
    u += 0x7fff + ((u >> 16) & 1);
    return (unsigned short)(u >> 16);
}

// ---------------- Kernel 0: RoPE cos/sin table [T][64] ----------------
__global__ __launch_bounds__(256) void rope_tab_kernel(float2* __restrict__ tab) {
    int i = blockIdx.x * 256 + threadIdx.x;     // i < 2048*64
    int t = i >> 6, j = i & 63;
    float theta = __powf(10000.f, -(float)j * (1.f / 32.f));
    float ang = (float)t * theta;
    tab[i] = make_float2(__cosf(ang), __sinf(ang));
}

// ---------------- Kernel 1: QKV projection + RoPE -> bf16 ----------------
// Outputs: qo bf16 [B,2,T,128], ko bf16 [B,T,128], vt bf16 [B,128,T]
__global__ __launch_bounds__(256) void qkv_rope_kernel(
    const float* __restrict__ x,
    const float* __restrict__ Wq,
    const float* __restrict__ Wk,
    const float* __restrict__ Wv,
    const float2* __restrict__ tab,
    unsigned short* __restrict__ qo,
    unsigned short* __restrict__ ko,
    unsigned short* __restrict__ vt)
{
    int row0 = blockIdx.x * RPB;
    int tid = threadIdx.x;

    __shared__ float4 xs[RPB * 256];   // 32 KB; reused as outs[RPB][512] later

    for (int i = tid; i < RPB * 256; i += 256) {
        int r = i >> 8, c = i & 255;
        xs[i] = ((const float4*)(x + (size_t)(row0 + r) * DD))[c];
    }
    __syncthreads();

    const float4* w0 = (const float4*)(Wq + (size_t)tid * DD);
    const float4* w1 = (tid < 128)
        ? (const float4*)(Wk + (size_t)tid * DD)
        : (const float4*)(Wv + (size_t)(tid - 128) * DD);

    float acc0[RPB], acc1[RPB];
    #pragma unroll
    for (int r = 0; r < RPB; ++r) { acc0[r] = 0.f; acc1[r] = 0.f; }

    for (int c = 0; c < 256; ++c) {
        float4 a = w0[c];
        float4 b = w1[c];
        #pragma unroll
        for (int r = 0; r < RPB; ++r) {
            float4 xv = xs[r * 256 + c];
            acc0[r] += xv.x * a.x + xv.y * a.y + xv.z * a.z + xv.w * a.w;
            acc1[r] += xv.x * b.x + xv.y * b.y + xv.z * b.z + xv.w * b.w;
        }
    }
    __syncthreads();

    float* outs = (float*)xs;          // [RPB][512]
    #pragma unroll
    for (int r = 0; r < RPB; ++r) {
        outs[r * 512 + tid] = acc0[r];
        outs[r * 512 + 256 + tid] = acc1[r];
    }
    __syncthreads();

    // RoPE on q (2 heads x 64 pairs) and k (64 pairs), fp32 table
    for (int i = tid; i < RPB * 192; i += 256) {
        int r = i / 192, j = i - r * 192;
        int t = (row0 + r) & (TT - 1);
        int base, pj;
        if (j < 128) { base = (j >> 6) * 128; pj = j & 63; }
        else         { base = 256;            pj = j - 128; }
        float2 cs = tab[t * 64 + pj];
        float* o = outs + r * 512 + base + 2 * pj;
        float x0 = o[0], x1 = o[1];
        o[0] = x0 * cs.x - x1 * cs.y;
        o[1] = x1 * cs.x + x0 * cs.y;
    }
    __syncthreads();

    int h = tid >> 7, hs = tid & 127;
    int b = row0 >> 11, t0 = row0 & (TT - 1);
    for (int r = 0; r < RPB; ++r) {
        int t = t0 + r;
        float* o = outs + r * 512;
        qo[(((size_t)b * 2 + h) * TT + t) * HSZ + hs] = f2bf(o[tid]);
        if (tid < 128) ko[((size_t)b * TT + t) * HSZ + tid] = f2bf(o[256 + tid]);
    }
    if (tid >= 128) {
        int d = tid - 128;
        unsigned short vv[8];
        #pragma unroll
        for (int r = 0; r < RPB; ++r) vv[r] = f2bf(outs[r * 512 + 384 + d]);
        *(uint4*)(vt + ((size_t)b * HSZ + d) * TT + t0) = *(uint4*)vv;
    }
}

// ---------------- Kernel 2: MFMA flash attention ----------------
// grid = 512 blocks (qt-major, load-balance-paired), 256 threads = 4 waves.
// Block: 32 queries (2 qsubs x 16) for one (b,h); waves split KV tiles by parity.
// att out fp32 [B,T,2,128]
__global__ __launch_bounds__(256) void attn_mfma_kernel(
    const unsigned short* __restrict__ q,
    const unsigned short* __restrict__ k,
    const unsigned short* __restrict__ vt,
    float* __restrict__ att)
{
    int bid = blockIdx.x;
    int rr = bid >> 3;
    int qt = (rr < 32) ? rr : 63 - (rr - 32);   // pair (i, 63-i) per CU for balance
    int bh = bid & 7;
    int b = bh >> 1, h = bh & 1;
    int q0 = qt * 32;
    int tid = threadIdx.x;
    int wave = tid >> 6, lane = tid & 63;
    int qsub = wave >> 1, par = wave & 1;
    int qw0 = q0 + qsub * 16;
    int mrow = lane & 15, quad = lane >> 4;

    // raw LDS; Os (merge) overlays Ks/Vs after the main loop
    __shared__ char raw[32768 + 4096 + 256];
    unsigned short* Ks0 = (unsigned short*)raw;            // [2][4096] frag-linear K tiles
    unsigned short* Vs0 = (unsigned short*)(raw + 16384);  // [2][4096] frag-linear V^T tiles
    unsigned short* Psb = (unsigned short*)(raw + 32768);  // [4][512] per-wave P
    float* Ms_ = (float*)(raw + 32768 + 4096);             // [2][16]
    float* Ls_ = Ms_ + 32;                                 // [2][16]
    float* Os  = (float*)raw;                              // [2][16*128] overlay

    // Q fragments: A[m=lane&15][k=quad*8+j], 4 k-chunks of 32
    const unsigned short* qrow = q + (((size_t)(b * 2 + h)) * TT + qw0 + mrow) * HSZ + quad * 8;
    bf16x8 qf[4];
    #pragma unroll
    for (int c = 0; c < 4; ++c) qf[c] = *(const bf16x8*)(qrow + 32 * c);

    float mrun[4], lrun[4];
    f32x4 O[8];
    #pragma unroll
    for (int r = 0; r < 4; ++r) { mrun[r] = -1e30f; lrun[r] = 0.f; }
    #pragma unroll
    for (int g = 0; g < 8; ++g)
        #pragma unroll
        for (int r = 0; r < 4; ++r) O[g][r] = 0.f;

    const int NT = qt + 1;                      // KV tiles of 32
    const unsigned short* kbase = k + (size_t)b * TT * HSZ;
    const unsigned short* vbase = vt + (size_t)b * HSZ * TT;
    const float scl = 0.08838834764831845f;

    for (int jj = 0; jj < NT; jj += 2) {
        __syncthreads();
        for (int tp = 0; tp < 2; ++tp) {
            int j = jj + tp;
            if (j >= NT) break;
            int s0 = j * 32;
            // K tile: [32][128] -> frag-linear chunks ((c*2+f)*64 + lane)
            const uint4* kg = (const uint4*)(kbase + (size_t)s0 * HSZ);
            uint4* kl = (uint4*)(Ks0 + tp * 4096);
            #pragma unroll
            for (int u = 0; u < 2; ++u) {
                int idx = tid + u * 256;
                int s = idx >> 4, cd = idx & 15;
                int chunk = ((cd >> 2) * 2 + (s >> 4)) * 64 + (cd & 3) * 16 + (s & 15);
                kl[chunk] = kg[idx];
            }
            // V^T tile: rows d, cols s0..s0+31 -> frag-linear chunks (g*64 + lane)
            uint4* vl = (uint4*)(Vs0 + tp * 4096);
            #pragma unroll
            for (int u = 0; u < 2; ++u) {
                int idx = tid + u * 256;
                int d = idx >> 2, cc = idx & 3;
                const uint4* vg = (const uint4*)(vbase + (size_t)d * TT + s0);
                int chunk = ((d >> 4) * 4 + cc) * 16 + (d & 15);
                vl[chunk] = vg[cc];
            }
        }
        __syncthreads();

        int j = jj + par;
        int s0 = j * 32;
        if (j < NT && s0 <= qw0 + 15) {
            const unsigned short* Kt = Ks0 + par * 4096;
            const unsigned short* Vtt = Vs0 + par * 4096;

            f32x4 S[2];
            #pragma unroll
            for (int f = 0; f < 2; ++f)
                #pragma unroll
                for (int r = 0; r < 4; ++r) S[f][r] = 0.f;

            #pragma unroll
            for (int c = 0; c < 4; ++c) {
                #pragma unroll
                for (int f = 0; f < 2; ++f) {
                    bf16x8 bk = *(const bf16x8*)(Kt + ((c * 2 + f) * 64 + lane) * 8);
                    S[f] = __builtin_amdgcn_mfma_f32_16x16x32_bf16(qf[c], bk, S[f], 0, 0, 0);
                }
            }

            // scale + causal mask (D layout: col=lane&15, row=quad*4+r)
            #pragma unroll
            for (int f = 0; f < 2; ++f) {
                int sg = s0 + 16 * f + mrow;
                #pragma unroll
                for (int r = 0; r < 4; ++r) {
                    int qg = qw0 + quad * 4 + r;
                    float val = S[f][r] * scl;
                    S[f][r] = (sg <= qg) ? val : -1e30f;
                }
            }

            // online softmax update
            float al[4];
            #pragma unroll
            for (int r = 0; r < 4; ++r) {
                float v = fmaxf(S[0][r], S[1][r]);
                v = fmaxf(v, __shfl_xor(v, 1, 64));
                v = fmaxf(v, __shfl_xor(v, 2, 64));
                v = fmaxf(v, __shfl_xor(v, 4, 64));
                v = fmaxf(v, __shfl_xor(v, 8, 64));
                float mn = fmaxf(mrun[r], v);
                al[r] = __expf(mrun[r] - mn);
                mrun[r] = mn;
            }
            #pragma unroll
            for (int f = 0; f < 2; ++f)
                #pragma unroll
                for (int r = 0; r < 4; ++r)
                    S[f][r] = __expf(S[f][r] - mrun[r]);
            #pragma unroll
            for (int r = 0; r < 4; ++r) {
                float v = S[0][r] + S[1][r];
                v += __shfl_xor(v, 1, 64);
                v += __shfl_xor(v, 2, 64);
                v += __shfl_xor(v, 4, 64);
                v += __shfl_xor(v, 8, 64);
                lrun[r] = lrun[r] * al[r] + v;
            }
            #pragma unroll
            for (int g = 0; g < 8; ++g) {
                O[g][0] *= al[0]; O[g][1] *= al[1]; O[g][2] *= al[2]; O[g][3] *= al[3];
            }

            // P -> LDS (frag-linear: chunk = (s>>3)*16 + q_row), read back as A-frag
            unsigned short* Pw = Psb + wave * 512;
            #pragma unroll
            for (int f = 0; f < 2; ++f) {
                int col = 16 * f + mrow;
                int hi = col >> 3, loj = col & 7;
                #pragma unroll
                for (int r = 0; r < 4; ++r)
                    Pw[(hi * 16 + quad * 4 + r) * 8 + loj] = f2bf(S[f][r]);
            }
            bf16x8 pa = *(const bf16x8*)(Pw + lane * 8);

            #pragma unroll
            for (int g = 0; g < 8; ++g) {
                bf16x8 bv = *(const bf16x8*)(Vtt + (g * 64 + lane) * 8);
                O[g] = __builtin_amdgcn_mfma_f32_16x16x32_bf16(pa, bv, O[g], 0, 0, 0);
            }
        }
    }

    // merge kv-parity partials per qsub
    __syncthreads();
    if (par == 1) {
        if (mrow == 0) {
            #pragma unroll
            for (int r = 0; r < 4; ++r) {
                Ms_[qsub * 16 + quad * 4 + r] = mrun[r];
                Ls_[qsub * 16 + quad * 4 + r] = lrun[r];
            }
        }
        float* Ow = Os + qsub * 16 * 128;
        #pragma unroll
        for (int g = 0; g < 8; ++g)
            #pragma unroll
            for (int r = 0; r < 4; ++r)
                Ow[(quad * 4 + r) * 128 + g * 16 + mrow] = O[g][r];
    }
    __syncthreads();
    if (par == 0) {
        const float* Op = Os + qsub * 16 * 128;
        float A0[4], A1[4], inv[4];
        #pragma unroll
        for (int r = 0; r < 4; ++r) {
            float m1 = Ms_[qsub * 16 + quad * 4 + r];
            float l1 = Ls_[qsub * 16 + quad * 4 + r];
            float m12 = fmaxf(mrun[r], m1);
            A0[r] = __expf(mrun[r] - m12);
            A1[r] = __expf(m1 - m12);
            inv[r] = 1.f / (lrun[r] * A0[r] + l1 * A1[r]);
        }
        float* ab = att + (((size_t)b * TT + qw0) * 2 + h) * 128;
        #pragma unroll
        for (int g = 0; g < 8; ++g)
            #pragma unroll
            for (int r = 0; r < 4; ++r) {
                int row = quad * 4 + r;
                float o = (O[g][r] * A0[r] + Op[row * 128 + g * 16 + mrow] * A1[r]) * inv[r];
                ab[(size_t)row * 256 + g * 16 + mrow] = o;
            }
    }
}

// ---------------- Kernel 3: output projection (fp32) ----------------
__global__ __launch_bounds__(256) void outproj_kernel(
    const float* __restrict__ att,
    const float* __restrict__ Wo,
    float* __restrict__ y)
{
    int row0 = blockIdx.x * RPB;
    int tid = threadIdx.x;

    __shared__ float4 as[RPB * 64];
    for (int i = tid; i < RPB * 64; i += 256)
        as[i] = ((const float4*)att)[(size_t)row0 * 64 + i];
    __syncthreads();

    #pragma unroll
    for (int oo = 0; oo < 4; ++oo) {
        int od = tid + (oo << 8);
        const float4* wr = (const float4*)(Wo + (size_t)od * 256);
        float acc[RPB];
        #pragma unroll
        for (int r = 0; r < RPB; ++r) acc[r] = 0.f;
        for (int c = 0; c < 64; ++c) {
            float4 w4 = wr[c];
            #pragma unroll
            for (int r = 0; r < RPB; ++r) {
                float4 a4 = as[r * 64 + c];
                acc[r] += a4.x * w4.x + a4.y * w4.y + a4.z * w4.z + a4.w * w4.w;
            }
        }
        #pragma unroll
        for (int r = 0; r < RPB; ++r)
            y[(size_t)(row0 + r) * DD + od] = acc[r];
    }
}

extern "C" void kernel_launch(void* const* d_in, const int* in_sizes, int n_in,
                              void* d_out, int out_size, void* d_ws, size_t ws_size,
                              hipStream_t stream) {
    const float* x  = (const float*)d_in[0];
    const float* Wq = (const float*)d_in[1];
    const float* Wk = (const float*)d_in[2];
    const float* Wv = (const float*)d_in[3];
    const float* Wo = (const float*)d_in[4];
    float* y = (float*)d_out;

    // ws: qo bf16 4MB | ko bf16 2MB | vt bf16 2MB | att fp32 8MB | rope tab 1MB
    char* ws = (char*)d_ws;
    unsigned short* qo = (unsigned short*)(ws);
    unsigned short* ko = (unsigned short*)(ws + 4u * 1024 * 1024);
    unsigned short* vt = (unsigned short*)(ws + 6u * 1024 * 1024);
    float*          at = (float*)         (ws + 8u * 1024 * 1024);
    float2*         tb = (float2*)        (ws + 16u * 1024 * 1024);

    rope_tab_kernel<<<512, 256, 0, stream>>>(tb);
    qkv_rope_kernel<<<NB * TT / RPB, 256, 0, stream>>>(x, Wq, Wk, Wv, tb, qo, ko, vt);
    attn_mfma_kernel<<<512, 256, 0, stream>>>(qo, ko, vt, at);
    outproj_kernel<<<NB * TT / RPB, 256, 0, stream>>>(at, Wo, y);
}

// Round 4
// 223.294 us; speedup vs baseline: 9.7871x; 3.5066x over previous
//
#include <hip/hip_runtime.h>
#include <math.h>

#define DD 1024
#define HSZ 128
#define NB 4
#define TT 2048

typedef __attribute__((ext_vector_type(8))) short bf16x8;
typedef __attribute__((ext_vector_type(4))) float f32x4;

__device__ inline unsigned short f2bf(float f){
    unsigned u = __builtin_bit_cast(unsigned, f);
    u += 0x7fff + ((u >> 16) & 1);
    return (unsigned short)(u >> 16);
}

// ---------------- k0: RoPE cos/sin table [T][64] ----------------
__global__ __launch_bounds__(256) void rope_tab_kernel(float2* __restrict__ tab) {
    int i = blockIdx.x * 256 + threadIdx.x;     // < 2048*64
    int t = i >> 6, j = i & 63;
    float theta = __powf(10000.f, -(float)j * (1.f / 32.f));
    float ang = (float)t * theta;
    tab[i] = make_float2(__cosf(ang), __sinf(ang));
}

// ---------------- k1: weights -> bf16 ----------------
// Wb = [Wq(256) ; Wk(128) ; Wv(128)] rows x 1024, Wob = Wo 1024 x 256
__global__ __launch_bounds__(256) void convw_kernel(
    const float* __restrict__ Wq, const float* __restrict__ Wk,
    const float* __restrict__ Wv, const float* __restrict__ Wo,
    unsigned short* __restrict__ Wb, unsigned short* __restrict__ Wob)
{
    int i = blockIdx.x * 256 + threadIdx.x;     // 384*256 threads, 8 elems each
    int e = i * 8;
    const float* src;
    unsigned short* dst;
    if (e < 512 * 1024) {
        int row = e >> 10, col = e & 1023;
        const float* s = (row < 256) ? Wq + (size_t)row * DD
                       : (row < 384) ? Wk + (size_t)(row - 256) * DD
                                     : Wv + (size_t)(row - 384) * DD;
        src = s + col;
        dst = Wb + e;
    } else {
        int e2 = e - 512 * 1024;
        src = Wo + e2;
        dst = Wob + e2;
    }
    float4 a = ((const float4*)src)[0];
    float4 c = ((const float4*)src)[1];
    unsigned short o[8] = {f2bf(a.x),f2bf(a.y),f2bf(a.z),f2bf(a.w),
                           f2bf(c.x),f2bf(c.y),f2bf(c.z),f2bf(c.w)};
    *(uint4*)dst = *(const uint4*)o;
}

// ---------------- k2: QKV MFMA GEMM + fused RoPE epilogue ----------------
// C[8192 x 512] = x(bf16-cast) @ Wb^T ; 128x128 tiles, BK=64.
// ct 0,1 -> q (h=ct), ct 2 -> k, ct 3 -> v (transposed store).
__global__ __launch_bounds__(256) void qkv_gemm_kernel(
    const float* __restrict__ x,
    const unsigned short* __restrict__ Wb,
    const float2* __restrict__ tab,
    unsigned short* __restrict__ qo,
    unsigned short* __restrict__ ko,
    unsigned short* __restrict__ vt)
{
    int bid = blockIdx.x;
    int rt = bid & 63, ct = bid >> 6;       // same-rt blocks share x-strip in L2
    int row0 = rt * 128;
    int b = row0 >> 11, t0 = row0 & (TT - 1);
    int tid = threadIdx.x;
    int wave = tid >> 6, lane = tid & 63;
    int mrow = lane & 15, quad = lane >> 4;

    __shared__ unsigned short As[8192];     // frag-linear 128x64 bf16
    __shared__ unsigned short Bs[8192];

    f32x4 acc[2][8];
    #pragma unroll
    for (int rs = 0; rs < 2; ++rs)
        #pragma unroll
        for (int ns = 0; ns < 8; ++ns)
            #pragma unroll
            for (int r = 0; r < 4; ++r) acc[rs][ns][r] = 0.f;

    for (int kk = 0; kk < 16; ++kk) {
        __syncthreads();
        // stage A: fp32 -> bf16, frag-linear
        #pragma unroll
        for (int u = 0; u < 4; ++u) {
            int idx = u * 256 + tid;
            int row = idx >> 3, c8 = idx & 7;
            const float4* src = (const float4*)(x + (size_t)(row0 + row) * DD + kk * 64 + c8 * 8);
            float4 f0 = src[0], f1 = src[1];
            bf16x8 pk;
            pk[0]=(short)f2bf(f0.x); pk[1]=(short)f2bf(f0.y); pk[2]=(short)f2bf(f0.z); pk[3]=(short)f2bf(f0.w);
            pk[4]=(short)f2bf(f1.x); pk[5]=(short)f2bf(f1.y); pk[6]=(short)f2bf(f1.z); pk[7]=(short)f2bf(f1.w);
            int w2 = row >> 5, rsub = (row >> 4) & 1, mr = row & 15;
            int kc = c8 >> 2, qd = c8 & 3;
            int ch = ((w2 * 2 + rsub) * 2 + kc) * 64 + qd * 16 + mr;
            *(bf16x8*)(As + ch * 8) = pk;
        }
        // stage B: bf16 copy, frag-linear
        #pragma unroll
        for (int u = 0; u < 4; ++u) {
            int ch = u * 256 + tid;
            int l6 = ch & 63, kc = (ch >> 6) & 1, ns = ch >> 7;
            int brow = ct * 128 + ns * 16 + (l6 & 15);
            int kcol = kk * 64 + kc * 32 + (l6 >> 4) * 8;
            *(uint4*)(Bs + ch * 8) = *(const uint4*)(Wb + (size_t)brow * DD + kcol);
        }
        __syncthreads();
        // compute: 2 k-chunks x (2 rs x 8 ns) MFMA
        #pragma unroll
        for (int kc = 0; kc < 2; ++kc) {
            bf16x8 af[2], bb[8];
            af[0] = *(const bf16x8*)(As + (((wave * 2 + 0) * 2 + kc) * 64 + lane) * 8);
            af[1] = *(const bf16x8*)(As + (((wave * 2 + 1) * 2 + kc) * 64 + lane) * 8);
            #pragma unroll
            for (int ns = 0; ns < 8; ++ns)
                bb[ns] = *(const bf16x8*)(Bs + ((ns * 2 + kc) * 64 + lane) * 8);
            #pragma unroll
            for (int rs = 0; rs < 2; ++rs)
                #pragma unroll
                for (int ns = 0; ns < 8; ++ns)
                    acc[rs][ns] = __builtin_amdgcn_mfma_f32_16x16x32_bf16(af[rs], bb[ns], acc[rs][ns], 0, 0, 0);
        }
    }

    int wrow0 = wave * 32;
    if (ct < 3) {
        // q (ct=0,1) / k (ct=2) with RoPE; pair partner lives in lane^1
        unsigned short* dst0 = (ct < 2) ? qo + ((size_t)(b * 2 + ct) * TT) * 128
                                        : ko + (size_t)b * TT * 128;
        #pragma unroll
        for (int rs = 0; rs < 2; ++rs) {
            #pragma unroll
            for (int ns = 0; ns < 8; ++ns) {
                int colloc = ns * 16 + mrow;
                int pj = colloc >> 1;
                #pragma unroll
                for (int r = 0; r < 4; ++r) {
                    int t = t0 + wrow0 + rs * 16 + quad * 4 + r;
                    float v = acc[rs][ns][r];
                    float vp = __shfl_xor(v, 1, 64);
                    float2 cs = tab[t * 64 + pj];
                    float outv = ((mrow & 1) == 0) ? (v * cs.x - vp * cs.y)
                                                   : (v * cs.x + vp * cs.y);
                    dst0[(size_t)t * 128 + colloc] = f2bf(outv);
                }
            }
        }
    } else {
        // v: transposed store vt[b][d][t], 4 t-values packed per 8B store
        #pragma unroll
        for (int rs = 0; rs < 2; ++rs) {
            #pragma unroll
            for (int ns = 0; ns < 8; ++ns) {
                int d = ns * 16 + mrow;
                unsigned short pk4[4];
                #pragma unroll
                for (int r = 0; r < 4; ++r) pk4[r] = f2bf(acc[rs][ns][r]);
                int t = t0 + wrow0 + rs * 16 + quad * 4;
                *(uint2*)(vt + ((size_t)(b * 128 + d)) * TT + t) = *(const uint2*)pk4;
            }
        }
    }
}

// ---------------- k3: MFMA flash attention (bf16 att out) ----------------
__global__ __launch_bounds__(256) void attn_mfma_kernel(
    const unsigned short* __restrict__ q,
    const unsigned short* __restrict__ k,
    const unsigned short* __restrict__ vt,
    unsigned short* __restrict__ att)
{
    int bid = blockIdx.x;
    int rr = bid >> 3;
    int qt = (rr < 32) ? rr : 63 - (rr - 32);
    int bh = bid & 7;
    int b = bh >> 1, h = bh & 1;
    int q0 = qt * 32;
    int tid = threadIdx.x;
    int wave = tid >> 6, lane = tid & 63;
    int qsub = wave >> 1, par = wave & 1;
    int qw0 = q0 + qsub * 16;
    int mrow = lane & 15, quad = lane >> 4;

    __shared__ char raw[32768 + 4096 + 256];
    unsigned short* Ks0 = (unsigned short*)raw;
    unsigned short* Vs0 = (unsigned short*)(raw + 16384);
    unsigned short* Psb = (unsigned short*)(raw + 32768);
    float* Ms_ = (float*)(raw + 32768 + 4096);
    float* Ls_ = Ms_ + 32;
    float* Os  = (float*)raw;

    const unsigned short* qrow = q + (((size_t)(b * 2 + h)) * TT + qw0 + mrow) * HSZ + quad * 8;
    bf16x8 qf[4];
    #pragma unroll
    for (int c = 0; c < 4; ++c) qf[c] = *(const bf16x8*)(qrow + 32 * c);

    float mrun[4], lrun[4];
    f32x4 O[8];
    #pragma unroll
    for (int r = 0; r < 4; ++r) { mrun[r] = -1e30f; lrun[r] = 0.f; }
    #pragma unroll
    for (int g = 0; g < 8; ++g)
        #pragma unroll
        for (int r = 0; r < 4; ++r) O[g][r] = 0.f;

    const int NT = qt + 1;
    const unsigned short* kbase = k + (size_t)b * TT * HSZ;
    const unsigned short* vbase = vt + (size_t)b * HSZ * TT;
    const float scl = 0.08838834764831845f;

    for (int jj = 0; jj < NT; jj += 2) {
        __syncthreads();
        for (int tp = 0; tp < 2; ++tp) {
            int j = jj + tp;
            if (j >= NT) break;
            int s0 = j * 32;
            const uint4* kg = (const uint4*)(kbase + (size_t)s0 * HSZ);
            uint4* kl = (uint4*)(Ks0 + tp * 4096);
            #pragma unroll
            for (int u = 0; u < 2; ++u) {
                int idx = tid + u * 256;
                int s = idx >> 4, cd = idx & 15;
                int chunk = ((cd >> 2) * 2 + (s >> 4)) * 64 + (cd & 3) * 16 + (s & 15);
                kl[chunk] = kg[idx];
            }
            uint4* vl = (uint4*)(Vs0 + tp * 4096);
            #pragma unroll
            for (int u = 0; u < 2; ++u) {
                int idx = tid + u * 256;
                int d = idx >> 2, cc = idx & 3;
                const uint4* vg = (const uint4*)(vbase + (size_t)d * TT + s0);
                int chunk = ((d >> 4) * 4 + cc) * 16 + (d & 15);
                vl[chunk] = vg[cc];
            }
        }
        __syncthreads();

        int j = jj + par;
        int s0 = j * 32;
        if (j < NT && s0 <= qw0 + 15) {
            const unsigned short* Kt = Ks0 + par * 4096;
            const unsigned short* Vtt = Vs0 + par * 4096;

            f32x4 S[2];
            #pragma unroll
            for (int f = 0; f < 2; ++f)
                #pragma unroll
                for (int r = 0; r < 4; ++r) S[f][r] = 0.f;

            #pragma unroll
            for (int c = 0; c < 4; ++c) {
                #pragma unroll
                for (int f = 0; f < 2; ++f) {
                    bf16x8 bk = *(const bf16x8*)(Kt + ((c * 2 + f) * 64 + lane) * 8);
                    S[f] = __builtin_amdgcn_mfma_f32_16x16x32_bf16(qf[c], bk, S[f], 0, 0, 0);
                }
            }

            #pragma unroll
            for (int f = 0; f < 2; ++f) {
                int sg = s0 + 16 * f + mrow;
                #pragma unroll
                for (int r = 0; r < 4; ++r) {
                    int qg = qw0 + quad * 4 + r;
                    float val = S[f][r] * scl;
                    S[f][r] = (sg <= qg) ? val : -1e30f;
                }
            }

            float al[4];
            #pragma unroll
            for (int r = 0; r < 4; ++r) {
                float v = fmaxf(S[0][r], S[1][r]);
                v = fmaxf(v, __shfl_xor(v, 1, 64));
                v = fmaxf(v, __shfl_xor(v, 2, 64));
                v = fmaxf(v, __shfl_xor(v, 4, 64));
                v = fmaxf(v, __shfl_xor(v, 8, 64));
                float mn = fmaxf(mrun[r], v);
                al[r] = __expf(mrun[r] - mn);
                mrun[r] = mn;
            }
            #pragma unroll
            for (int f = 0; f < 2; ++f)
                #pragma unroll
                for (int r = 0; r < 4; ++r)
                    S[f][r] = __expf(S[f][r] - mrun[r]);
            #pragma unroll
            for (int r = 0; r < 4; ++r) {
                float v = S[0][r] + S[1][r];
                v += __shfl_xor(v, 1, 64);
                v += __shfl_xor(v, 2, 64);
                v += __shfl_xor(v, 4, 64);
                v += __shfl_xor(v, 8, 64);
                lrun[r] = lrun[r] * al[r] + v;
            }
            #pragma unroll
            for (int g = 0; g < 8; ++g) {
                O[g][0] *= al[0]; O[g][1] *= al[1]; O[g][2] *= al[2]; O[g][3] *= al[3];
            }

            unsigned short* Pw = Psb + wave * 512;
            #pragma unroll
            for (int f = 0; f < 2; ++f) {
                int col = 16 * f + mrow;
                int hi = col >> 3, loj = col & 7;
                #pragma unroll
                for (int r = 0; r < 4; ++r)
                    Pw[(hi * 16 + quad * 4 + r) * 8 + loj] = f2bf(S[f][r]);
            }
            bf16x8 pa = *(const bf16x8*)(Pw + lane * 8);

            #pragma unroll
            for (int g = 0; g < 8; ++g) {
                bf16x8 bv = *(const bf16x8*)(Vtt + (g * 64 + lane) * 8);
                O[g] = __builtin_amdgcn_mfma_f32_16x16x32_bf16(pa, bv, O[g], 0, 0, 0);
            }
        }
    }

    __syncthreads();
    if (par == 1) {
        if (mrow == 0) {
            #pragma unroll
            for (int r = 0; r < 4; ++r) {
                Ms_[qsub * 16 + quad * 4 + r] = mrun[r];
                Ls_[qsub * 16 + quad * 4 + r] = lrun[r];
            }
        }
        float* Ow = Os + qsub * 16 * 128;
        #pragma unroll
        for (int g = 0; g < 8; ++g)
            #pragma unroll
            for (int r = 0; r < 4; ++r)
                Ow[(quad * 4 + r) * 128 + g * 16 + mrow] = O[g][r];
    }
    __syncthreads();
    if (par == 0) {
        const float* Op = Os + qsub * 16 * 128;
        float A0[4], A1[4], inv[4];
        #pragma unroll
        for (int r = 0; r < 4; ++r) {
            float m1 = Ms_[qsub * 16 + quad * 4 + r];
            float l1 = Ls_[qsub * 16 + quad * 4 + r];
            float m12 = fmaxf(mrun[r], m1);
            A0[r] = __expf(mrun[r] - m12);
            A1[r] = __expf(m1 - m12);
            inv[r] = 1.f / (lrun[r] * A0[r] + l1 * A1[r]);
        }
        unsigned short* ab = att + (((size_t)b * TT + qw0) * 2 + h) * 128;
        #pragma unroll
        for (int g = 0; g < 8; ++g)
            #pragma unroll
            for (int r = 0; r < 4; ++r) {
                int row = quad * 4 + r;
                float o = (O[g][r] * A0[r] + Op[row * 128 + g * 16 + mrow] * A1[r]) * inv[r];
                ab[(size_t)row * 256 + g * 16 + mrow] = f2bf(o);
            }
    }
}

// ---------------- k4: output projection MFMA GEMM ----------------
// y[8192 x 1024] = att(bf16) @ Wob^T, K=256, fp32 out
__global__ __launch_bounds__(256) void outproj_gemm_kernel(
    const unsigned short* __restrict__ attb,
    const unsigned short* __restrict__ Wob,
    float* __restrict__ y)
{
    int bid = blockIdx.x;
    int rt = bid & 63, ct = bid >> 6;       // ct 0..7
    int row0 = rt * 128;
    int tid = threadIdx.x;
    int wave = tid >> 6, lane = tid & 63;
    int mrow = lane & 15, quad = lane >> 4;

    __shared__ unsigned short As[8192];
    __shared__ unsigned short Bs[8192];

    f32x4 acc[2][8];
    #pragma unroll
    for (int rs = 0; rs < 2; ++rs)
        #pragma unroll
        for (int ns = 0; ns < 8; ++ns)
            #pragma unroll
            for (int r = 0; r < 4; ++r) acc[rs][ns][r] = 0.f;

    for (int kk = 0; kk < 4; ++kk) {
        __syncthreads();
        #pragma unroll
        for (int u = 0; u < 4; ++u) {
            int ch = u * 256 + tid;
            int l6 = ch & 63, kc = (ch >> 6) & 1, rsub = (ch >> 7) & 1, w2 = ch >> 8;
            int arow = row0 + w2 * 32 + rsub * 16 + (l6 & 15);
            int kcol = kk * 64 + kc * 32 + (l6 >> 4) * 8;
            *(uint4*)(As + ch * 8) = *(const uint4*)(attb + (size_t)arow * 256 + kcol);
        }
        #pragma unroll
        for (int u = 0; u < 4; ++u) {
            int ch = u * 256 + tid;
            int l6 = ch & 63, kc = (ch >> 6) & 1, ns = ch >> 7;
            int brow = ct * 128 + ns * 16 + (l6 & 15);
            int kcol = kk * 64 + kc * 32 + (l6 >> 4) * 8;
            *(uint4*)(Bs + ch * 8) = *(const uint4*)(Wob + (size_t)brow * 256 + kcol);
        }
        __syncthreads();
        #pragma unroll
        for (int kc = 0; kc < 2; ++kc) {
            bf16x8 af[2], bb[8];
            af[0] = *(const bf16x8*)(As + (((wave * 2 + 0) * 2 + kc) * 64 + lane) * 8);
            af[1] = *(const bf16x8*)(As + (((wave * 2 + 1) * 2 + kc) * 64 + lane) * 8);
            #pragma unroll
            for (int ns = 0; ns < 8; ++ns)
                bb[ns] = *(const bf16x8*)(Bs + ((ns * 2 + kc) * 64 + lane) * 8);
            #pragma unroll
            for (int rs = 0; rs < 2; ++rs)
                #pragma unroll
                for (int ns = 0; ns < 8; ++ns)
                    acc[rs][ns] = __builtin_amdgcn_mfma_f32_16x16x32_bf16(af[rs], bb[ns], acc[rs][ns], 0, 0, 0);
        }
    }

    int wrow0 = wave * 32;
    #pragma unroll
    for (int rs = 0; rs < 2; ++rs)
        #pragma unroll
        for (int ns = 0; ns < 8; ++ns)
            #pragma unroll
            for (int r = 0; r < 4; ++r) {
                int row = row0 + wrow0 + rs * 16 + quad * 4 + r;
                y[(size_t)row * DD + ct * 128 + ns * 16 + mrow] = acc[rs][ns][r];
            }
}

extern "C" void kernel_launch(void* const* d_in, const int* in_sizes, int n_in,
                              void* d_out, int out_size, void* d_ws, size_t ws_size,
                              hipStream_t stream) {
    const float* x  = (const float*)d_in[0];
    const float* Wq = (const float*)d_in[1];
    const float* Wk = (const float*)d_in[2];
    const float* Wv = (const float*)d_in[3];
    const float* Wo = (const float*)d_in[4];
    float* y = (float*)d_out;

    // ws (bf16 unless noted): Wb 1MB | Wob 0.5MB | qo 4MB | ko 2MB | vt 2MB | att 4MB | tab 1MB
    char* ws = (char*)d_ws;
    unsigned short* Wb  = (unsigned short*)(ws);
    unsigned short* Wob = (unsigned short*)(ws + 1u * 1024 * 1024);
    unsigned short* qo  = (unsigned short*)(ws + 1536u * 1024);
    unsigned short* ko  = (unsigned short*)(ws + 5632u * 1024);
    unsigned short* vt  = (unsigned short*)(ws + 7680u * 1024);
    unsigned short* at  = (unsigned short*)(ws + 9728u * 1024);
    float2*         tb  = (float2*)        (ws + 13824u * 1024);

    rope_tab_kernel<<<512, 256, 0, stream>>>(tb);
    convw_kernel<<<384, 256, 0, stream>>>(Wq, Wk, Wv, Wo, Wb, Wob);
    qkv_gemm_kernel<<<256, 256, 0, stream>>>(x, Wb, tb, qo, ko, vt);
    attn_mfma_kernel<<<512, 256, 0, stream>>>(qo, ko, vt, at);
    outproj_gemm_kernel<<<512, 256, 0, stream>>>(at, Wob, y);
}

// Round 5
// 212.246 us; speedup vs baseline: 10.2966x; 1.0521x over previous
//
#include <hip/hip_runtime.h>
#include <math.h>

#define DD 1024
#define HSZ 128
#define NB 4
#define TT 2048

typedef __attribute__((ext_vector_type(8))) short bf16x8;
typedef __attribute__((ext_vector_type(4))) float f32x4;

__device__ inline unsigned short f2bf(float f){
    unsigned u = __builtin_bit_cast(unsigned, f);
    u += 0x7fff + ((u >> 16) & 1);
    return (unsigned short)(u >> 16);
}

// ---------------- k0: prep = RoPE table + weight bf16 conversion ----------------
// bid < 512: rope table [2048][64]; bid >= 512: convert weights
__global__ __launch_bounds__(256) void prep_kernel(
    const float* __restrict__ Wq, const float* __restrict__ Wk,
    const float* __restrict__ Wv, const float* __restrict__ Wo,
    unsigned short* __restrict__ Wb, unsigned short* __restrict__ Wob,
    float2* __restrict__ tab)
{
    int bid = blockIdx.x;
    if (bid < 512) {
        int i = bid * 256 + threadIdx.x;
        int t = i >> 6, j = i & 63;
        float theta = __powf(10000.f, -(float)j * (1.f / 32.f));
        float ang = (float)t * theta;
        tab[i] = make_float2(__cosf(ang), __sinf(ang));
        return;
    }
    int i = (bid - 512) * 256 + threadIdx.x;
    int e = i * 8;
    const float* src;
    unsigned short* dst;
    if (e < 512 * 1024) {
        int row = e >> 10;
        const float* s = (row < 256) ? Wq + (size_t)row * DD
                       : (row < 384) ? Wk + (size_t)(row - 256) * DD
                                     : Wv + (size_t)(row - 384) * DD;
        src = s + (e & 1023);
        dst = Wb + e;
    } else {
        int e2 = e - 512 * 1024;
        src = Wo + e2;
        dst = Wob + e2;
    }
    float4 a = ((const float4*)src)[0];
    float4 c = ((const float4*)src)[1];
    unsigned short o[8] = {f2bf(a.x),f2bf(a.y),f2bf(a.z),f2bf(a.w),
                           f2bf(c.x),f2bf(c.y),f2bf(c.z),f2bf(c.w)};
    *(uint4*)dst = *(const uint4*)o;
}

// ---------------- k1: QKV MFMA GEMM + fused RoPE, 64x128 tiles ----------------
// C[8192 x 512] = x(bf16) @ Wb^T. rt=bid&127 (64-row strip), ct=bid>>7.
__global__ __launch_bounds__(256) void qkv_gemm_kernel(
    const float* __restrict__ x,
    const unsigned short* __restrict__ Wb,
    const float2* __restrict__ tab,
    unsigned short* __restrict__ qo,
    unsigned short* __restrict__ ko,
    unsigned short* __restrict__ vt)
{
    int bid = blockIdx.x;
    int rt = bid & 127, ct = bid >> 7;
    int row0 = rt * 64;
    int b = row0 >> 11, t0 = row0 & (TT - 1);
    int tid = threadIdx.x;
    int wave = tid >> 6, lane = tid & 63;
    int mrow = lane & 15, quad = lane >> 4;

    __shared__ unsigned short As[4096];   // 64x64 bf16 frag-linear
    __shared__ unsigned short Bs[8192];   // 128x64 bf16 frag-linear

    f32x4 acc[8];
    #pragma unroll
    for (int ns = 0; ns < 8; ++ns)
        #pragma unroll
        for (int r = 0; r < 4; ++r) acc[ns][r] = 0.f;

    for (int kk = 0; kk < 16; ++kk) {
        __syncthreads();
        // A: 64 rows x 64 cols fp32 -> bf16
        #pragma unroll
        for (int u = 0; u < 2; ++u) {
            int idx = u * 256 + tid;
            int row = idx >> 3, c8 = idx & 7;
            const float4* src = (const float4*)(x + (size_t)(row0 + row) * DD + kk * 64 + c8 * 8);
            float4 f0 = src[0], f1 = src[1];
            bf16x8 pk;
            pk[0]=(short)f2bf(f0.x); pk[1]=(short)f2bf(f0.y); pk[2]=(short)f2bf(f0.z); pk[3]=(short)f2bf(f0.w);
            pk[4]=(short)f2bf(f1.x); pk[5]=(short)f2bf(f1.y); pk[6]=(short)f2bf(f1.z); pk[7]=(short)f2bf(f1.w);
            int ch = ((row >> 4) * 2 + (c8 >> 2)) * 64 + (c8 & 3) * 16 + (row & 15);
            *(bf16x8*)(As + ch * 8) = pk;
        }
        // B: 128 rows x 64 cols bf16 copy (LDS-contiguous writes)
        #pragma unroll
        for (int u = 0; u < 4; ++u) {
            int ch = u * 256 + tid;
            int l6 = ch & 63;
            int brow = ct * 128 + (ch >> 7) * 16 + (l6 & 15);
            int kcol = kk * 64 + ((ch >> 6) & 1) * 32 + (l6 >> 4) * 8;
            *(uint4*)(Bs + ch * 8) = *(const uint4*)(Wb + (size_t)brow * DD + kcol);
        }
        __syncthreads();
        #pragma unroll
        for (int kc = 0; kc < 2; ++kc) {
            bf16x8 af = *(const bf16x8*)(As + (((wave * 2 + kc)) * 64 + lane) * 8);
            #pragma unroll
            for (int ns = 0; ns < 8; ++ns) {
                bf16x8 bb = *(const bf16x8*)(Bs + ((ns * 2 + kc) * 64 + lane) * 8);
                acc[ns] = __builtin_amdgcn_mfma_f32_16x16x32_bf16(af, bb, acc[ns], 0, 0, 0);
            }
        }
    }

    if (ct < 3) {
        unsigned short* dst0 = (ct < 2) ? qo + ((size_t)(b * 2 + ct) * TT) * 128
                                        : ko + (size_t)b * TT * 128;
        #pragma unroll
        for (int ns = 0; ns < 8; ++ns) {
            int colloc = ns * 16 + mrow;
            int pj = colloc >> 1;
            #pragma unroll
            for (int r = 0; r < 4; ++r) {
                int t = t0 + wave * 16 + quad * 4 + r;
                float v = acc[ns][r];
                float vp = __shfl_xor(v, 1, 64);
                float2 cs = tab[t * 64 + pj];
                float outv = ((mrow & 1) == 0) ? (v * cs.x - vp * cs.y)
                                               : (v * cs.x + vp * cs.y);
                dst0[(size_t)t * 128 + colloc] = f2bf(outv);
            }
        }
    } else {
        #pragma unroll
        for (int ns = 0; ns < 8; ++ns) {
            int d = ns * 16 + mrow;
            unsigned short pk4[4];
            #pragma unroll
            for (int r = 0; r < 4; ++r) pk4[r] = f2bf(acc[ns][r]);
            int t = t0 + wave * 16 + quad * 4;
            *(uint2*)(vt + ((size_t)(b * 128 + d)) * TT + t) = *(const uint2*)pk4;
        }
    }
}

// ---------------- k2: MFMA flash attention, 64-wide KV tiles ----------------
__global__ __launch_bounds__(256) void attn_mfma_kernel(
    const unsigned short* __restrict__ q,
    const unsigned short* __restrict__ k,
    const unsigned short* __restrict__ vt,
    unsigned short* __restrict__ att)
{
    int bid = blockIdx.x;
    int rr = bid >> 3;
    int qt = (rr < 32) ? rr : 63 - (rr - 32);   // (i, 63-i) pairs land on same CU
    int bh = bid & 7;
    int b = bh >> 1, h = bh & 1;
    int q0 = qt * 32;
    int tid = threadIdx.x;
    int wave = tid >> 6, lane = tid & 63;
    int qsub = wave >> 1, par = wave & 1;
    int qw0 = q0 + qsub * 16;
    int mrow = lane & 15, quad = lane >> 4;

    __shared__ char raw[74240];
    unsigned short* Ks0 = (unsigned short*)raw;            // [2][8192] 64x128 K tiles
    unsigned short* Vs0 = (unsigned short*)(raw + 32768);  // [2][8192] 128x64 V^T tiles
    unsigned short* Psb = (unsigned short*)(raw + 65536);  // [4][1024]
    float* Ms_ = (float*)(raw + 73728);
    float* Ls_ = Ms_ + 32;
    float* Os  = (float*)raw;                              // overlay (16 KB)

    const unsigned short* qrow = q + (((size_t)(b * 2 + h)) * TT + qw0 + mrow) * HSZ + quad * 8;
    bf16x8 qf[4];
    #pragma unroll
    for (int c = 0; c < 4; ++c) qf[c] = *(const bf16x8*)(qrow + 32 * c);

    float mrun[4], lrun[4];
    f32x4 O[8];
    #pragma unroll
    for (int r = 0; r < 4; ++r) { mrun[r] = -1e30f; lrun[r] = 0.f; }
    #pragma unroll
    for (int g = 0; g < 8; ++g)
        #pragma unroll
        for (int r = 0; r < 4; ++r) O[g][r] = 0.f;

    const int NT = (qt + 2) >> 1;               // 64-wide tiles
    const unsigned short* kbase = k + (size_t)b * TT * HSZ;
    const unsigned short* vbase = vt + (size_t)b * HSZ * TT;
    const float scl = 0.08838834764831845f;

    for (int jj = 0; jj < NT; jj += 2) {
        __syncthreads();
        for (int tp = 0; tp < 2; ++tp) {
            int j = jj + tp;
            if (j >= NT) break;
            int s0 = j * 64;
            // K tile 64x128
            const uint4* kg = (const uint4*)(kbase + (size_t)s0 * HSZ);
            uint4* kl = (uint4*)(Ks0 + tp * 8192);
            #pragma unroll
            for (int u = 0; u < 4; ++u) {
                int idx = tid + u * 256;
                int s = idx >> 4, cd = idx & 15;
                int chunk = ((cd >> 2) * 4 + (s >> 4)) * 64 + (cd & 3) * 16 + (s & 15);
                kl[chunk] = kg[s * 16 + cd];
            }
            // V^T tile 128 x 64
            const uint4* vg = (const uint4*)(vbase + s0);
            uint4* vl = (uint4*)(Vs0 + tp * 8192);
            #pragma unroll
            for (int u = 0; u < 4; ++u) {
                int idx = tid + u * 256;
                int d = idx >> 3, cc = idx & 7;
                int chunk = ((d >> 4) * 2 + (cc >> 2)) * 64 + (cc & 3) * 16 + (d & 15);
                vl[chunk] = vg[d * (TT / 8) + cc];
            }
        }
        __syncthreads();

        int j = jj + par;
        int s0 = j * 64;
        if (j < NT && s0 <= qw0 + 15) {
            const unsigned short* Kt = Ks0 + par * 8192;
            const unsigned short* Vtt = Vs0 + par * 8192;

            f32x4 S[4];
            #pragma unroll
            for (int f = 0; f < 4; ++f)
                #pragma unroll
                for (int r = 0; r < 4; ++r) S[f][r] = 0.f;

            #pragma unroll
            for (int c = 0; c < 4; ++c)
                #pragma unroll
                for (int f = 0; f < 4; ++f) {
                    bf16x8 bk = *(const bf16x8*)(Kt + ((c * 4 + f) * 64 + lane) * 8);
                    S[f] = __builtin_amdgcn_mfma_f32_16x16x32_bf16(qf[c], bk, S[f], 0, 0, 0);
                }

            #pragma unroll
            for (int f = 0; f < 4; ++f) {
                int sg = s0 + 16 * f + mrow;
                #pragma unroll
                for (int r = 0; r < 4; ++r) {
                    int qg = qw0 + quad * 4 + r;
                    float val = S[f][r] * scl;
                    S[f][r] = (sg <= qg) ? val : -1e30f;
                }
            }

            float al[4];
            #pragma unroll
            for (int r = 0; r < 4; ++r) {
                float v = fmaxf(fmaxf(S[0][r], S[1][r]), fmaxf(S[2][r], S[3][r]));
                v = fmaxf(v, __shfl_xor(v, 1, 64));
                v = fmaxf(v, __shfl_xor(v, 2, 64));
                v = fmaxf(v, __shfl_xor(v, 4, 64));
                v = fmaxf(v, __shfl_xor(v, 8, 64));
                float mn = fmaxf(mrun[r], v);
                al[r] = __expf(mrun[r] - mn);
                mrun[r] = mn;
            }
            #pragma unroll
            for (int f = 0; f < 4; ++f)
                #pragma unroll
                for (int r = 0; r < 4; ++r)
                    S[f][r] = __expf(S[f][r] - mrun[r]);
            #pragma unroll
            for (int r = 0; r < 4; ++r) {
                float v = (S[0][r] + S[1][r]) + (S[2][r] + S[3][r]);
                v += __shfl_xor(v, 1, 64);
                v += __shfl_xor(v, 2, 64);
                v += __shfl_xor(v, 4, 64);
                v += __shfl_xor(v, 8, 64);
                lrun[r] = lrun[r] * al[r] + v;
            }
            #pragma unroll
            for (int g = 0; g < 8; ++g) {
                O[g][0] *= al[0]; O[g][1] *= al[1]; O[g][2] *= al[2]; O[g][3] *= al[3];
            }

            // P (16x64) -> LDS in A-frag linear form
            unsigned short* Pw = Psb + wave * 1024;
            #pragma unroll
            for (int f = 0; f < 4; ++f) {
                int p = f >> 1;
                int hi2 = (2 * f + (mrow >> 3)) & 3;
                int jlo = mrow & 7;
                #pragma unroll
                for (int r = 0; r < 4; ++r)
                    Pw[(p * 64 + hi2 * 16 + quad * 4 + r) * 8 + jlo] = f2bf(S[f][r]);
            }
            bf16x8 pa[2];
            pa[0] = *(const bf16x8*)(Pw + lane * 8);
            pa[1] = *(const bf16x8*)(Pw + (64 + lane) * 8);

            #pragma unroll
            for (int g = 0; g < 8; ++g)
                #pragma unroll
                for (int p = 0; p < 2; ++p) {
                    bf16x8 bv = *(const bf16x8*)(Vtt + ((g * 2 + p) * 64 + lane) * 8);
                    O[g] = __builtin_amdgcn_mfma_f32_16x16x32_bf16(pa[p], bv, O[g], 0, 0, 0);
                }
        }
    }

    __syncthreads();
    if (par == 1) {
        if (mrow == 0) {
            #pragma unroll
            for (int r = 0; r < 4; ++r) {
                Ms_[qsub * 16 + quad * 4 + r] = mrun[r];
                Ls_[qsub * 16 + quad * 4 + r] = lrun[r];
            }
        }
        float* Ow = Os + qsub * 2048;
        #pragma unroll
        for (int g = 0; g < 8; ++g)
            #pragma unroll
            for (int r = 0; r < 4; ++r)
                Ow[(quad * 4 + r) * 128 + g * 16 + mrow] = O[g][r];
    }
    __syncthreads();
    if (par == 0) {
        const float* Op = Os + qsub * 2048;
        float A0[4], A1[4], inv[4];
        #pragma unroll
        for (int r = 0; r < 4; ++r) {
            float m1 = Ms_[qsub * 16 + quad * 4 + r];
            float l1 = Ls_[qsub * 16 + quad * 4 + r];
            float m12 = fmaxf(mrun[r], m1);
            A0[r] = __expf(mrun[r] - m12);
            A1[r] = __expf(m1 - m12);
            inv[r] = 1.f / (lrun[r] * A0[r] + l1 * A1[r]);
        }
        unsigned short* ab = att + (((size_t)b * TT + qw0) * 2 + h) * 128;
        #pragma unroll
        for (int g = 0; g < 8; ++g)
            #pragma unroll
            for (int r = 0; r < 4; ++r) {
                int row = quad * 4 + r;
                float o = (O[g][r] * A0[r] + Op[row * 128 + g * 16 + mrow] * A1[r]) * inv[r];
                ab[(size_t)row * 256 + g * 16 + mrow] = f2bf(o);
            }
    }
}

// ---------------- k3: output projection GEMM, 64x128 tiles ----------------
__global__ __launch_bounds__(256) void outproj_gemm_kernel(
    const unsigned short* __restrict__ attb,
    const unsigned short* __restrict__ Wob,
    float* __restrict__ y)
{
    int bid = blockIdx.x;
    int rt = bid & 127, ct = bid >> 7;   // ct 0..7
    int row0 = rt * 64;
    int tid = threadIdx.x;
    int wave = tid >> 6, lane = tid & 63;
    int mrow = lane & 15, quad = lane >> 4;

    __shared__ unsigned short As[4096];
    __shared__ unsigned short Bs[8192];

    f32x4 acc[8];
    #pragma unroll
    for (int ns = 0; ns < 8; ++ns)
        #pragma unroll
        for (int r = 0; r < 4; ++r) acc[ns][r] = 0.f;

    for (int kk = 0; kk < 4; ++kk) {
        __syncthreads();
        #pragma unroll
        for (int u = 0; u < 2; ++u) {
            int ch = u * 256 + tid;
            int l6 = ch & 63;
            int arow = row0 + (ch >> 7) * 16 + (l6 & 15);
            int kcol = kk * 64 + ((ch >> 6) & 1) * 32 + (l6 >> 4) * 8;
            *(uint4*)(As + ch * 8) = *(const uint4*)(attb + (size_t)arow * 256 + kcol);
        }
        #pragma unroll
        for (int u = 0; u < 4; ++u) {
            int ch = u * 256 + tid;
            int l6 = ch & 63;
            int brow = ct * 128 + (ch >> 7) * 16 + (l6 & 15);
            int kcol = kk * 64 + ((ch >> 6) & 1) * 32 + (l6 >> 4) * 8;
            *(uint4*)(Bs + ch * 8) = *(const uint4*)(Wob + (size_t)brow * 256 + kcol);
        }
        __syncthreads();
        #pragma unroll
        for (int kc = 0; kc < 2; ++kc) {
            bf16x8 af = *(const bf16x8*)(As + ((wave * 2 + kc) * 64 + lane) * 8);
            #pragma unroll
            for (int ns = 0; ns < 8; ++ns) {
                bf16x8 bb = *(const bf16x8*)(Bs + ((ns * 2 + kc) * 64 + lane) * 8);
                acc[ns] = __builtin_amdgcn_mfma_f32_16x16x32_bf16(af, bb, acc[ns], 0, 0, 0);
            }
        }
    }

    #pragma unroll
    for (int ns = 0; ns < 8; ++ns)
        #pragma unroll
        for (int r = 0; r < 4; ++r) {
            int row = row0 + wave * 16 + quad * 4 + r;
            y[(size_t)row * DD + ct * 128 + ns * 16 + mrow] = acc[ns][r];
        }
}

extern "C" void kernel_launch(void* const* d_in, const int* in_sizes, int n_in,
                              void* d_out, int out_size, void* d_ws, size_t ws_size,
                              hipStream_t stream) {
    const float* x  = (const float*)d_in[0];
    const float* Wq = (const float*)d_in[1];
    const float* Wk = (const float*)d_in[2];
    const float* Wv = (const float*)d_in[3];
    const float* Wo = (const float*)d_in[4];
    float* y = (float*)d_out;

    char* ws = (char*)d_ws;
    unsigned short* Wb  = (unsigned short*)(ws);
    unsigned short* Wob = (unsigned short*)(ws + 1u * 1024 * 1024);
    unsigned short* qo  = (unsigned short*)(ws + 1536u * 1024);
    unsigned short* ko  = (unsigned short*)(ws + 5632u * 1024);
    unsigned short* vt  = (unsigned short*)(ws + 7680u * 1024);
    unsigned short* at  = (unsigned short*)(ws + 9728u * 1024);
    float2*         tb  = (float2*)        (ws + 13824u * 1024);

    prep_kernel<<<896, 256, 0, stream>>>(Wq, Wk, Wv, Wo, Wb, Wob, tb);
    qkv_gemm_kernel<<<512, 256, 0, stream>>>(x, Wb, tb, qo, ko, vt);
    attn_mfma_kernel<<<512, 256, 0, stream>>>(qo, ko, vt, at);
    outproj_gemm_kernel<<<1024, 256, 0, stream>>>(at, Wob, y);
}

// Round 7
// 167.432 us; speedup vs baseline: 13.0525x; 1.2677x over previous
//
#include <hip/hip_runtime.h>
#include <math.h>

#define DD 1024
#define HSZ 128
#define NB 4
#define TT 2048

typedef __attribute__((ext_vector_type(8))) short bf16x8;
typedef __attribute__((ext_vector_type(4))) float f32x4;

typedef __attribute__((address_space(3))) unsigned int lds_u32_t;
typedef __attribute__((address_space(1))) unsigned int glb_u32_t;

__device__ inline void gll16(const void* g, void* l) {
    __builtin_amdgcn_global_load_lds((const glb_u32_t*)g, (lds_u32_t*)l, 16, 0, 0);
}

__device__ inline unsigned short f2bf(float f){
    unsigned u = __builtin_bit_cast(unsigned, f);
    u += 0x7fff + ((u >> 16) & 1);
    return (unsigned short)(u >> 16);
}

// ---------------- k0: prep = RoPE table + frag-linear weight tiles ----------------
__global__ __launch_bounds__(256) void prep_kernel(
    const float* __restrict__ Wq, const float* __restrict__ Wk,
    const float* __restrict__ Wv, const float* __restrict__ Wo,
    unsigned short* __restrict__ Wbp, unsigned short* __restrict__ Wop,
    float2* __restrict__ tab)
{
    int bid = blockIdx.x, tid = threadIdx.x;
    if (bid < 512) {
        int i = bid * 256 + tid;
        int t = i >> 6, j = i & 63;
        float theta = __powf(10000.f, -(float)j * (1.f / 32.f));
        float ang = (float)t * theta;
        tab[i] = make_float2(__cosf(ang), __sinf(ang));
        return;
    }
    const float* s;
    unsigned short* dst;
    if (bid < 768) {
        int gc = (bid - 512) * 256 + tid;          // < 65536
        int tileid = gc >> 10;
        int ct = tileid >> 4, kk = tileid & 15;
        int ch = gc & 1023;
        int ns = ch >> 7, kc = (ch >> 6) & 1, l6 = ch & 63;
        int wrow = ct * 128 + ns * 16 + (l6 & 15);
        int kcol = kk * 64 + kc * 32 + (l6 >> 4) * 8;
        s = (wrow < 256) ? Wq + (size_t)wrow * DD
          : (wrow < 384) ? Wk + (size_t)(wrow - 256) * DD
                         : Wv + (size_t)(wrow - 384) * DD;
        s += kcol;
        dst = Wbp + (size_t)gc * 8;
    } else {
        int gc = (bid - 768) * 256 + tid;          // < 32768
        int tileid = gc >> 10;
        int ct = tileid >> 2, kk = tileid & 3;
        int ch = gc & 1023;
        int ns = ch >> 7, kc = (ch >> 6) & 1, l6 = ch & 63;
        int orow = ct * 128 + ns * 16 + (l6 & 15);
        int kcol = kk * 64 + kc * 32 + (l6 >> 4) * 8;
        s = Wo + (size_t)orow * 256 + kcol;
        dst = Wop + (size_t)gc * 8;
    }
    float4 a = ((const float4*)s)[0];
    float4 c = ((const float4*)s)[1];
    unsigned short o[8] = {f2bf(a.x),f2bf(a.y),f2bf(a.z),f2bf(a.w),
                           f2bf(c.x),f2bf(c.y),f2bf(c.z),f2bf(c.w)};
    *(uint4*)dst = *(const uint4*)o;
}

// ---------------- k1: QKV GEMM, 64x128 tiles, A direct-frag, B via global_load_lds ----
__global__ __launch_bounds__(256) void qkv_gemm_kernel(
    const float* __restrict__ x,
    const unsigned short* __restrict__ Wbp,
    const float2* __restrict__ tab,
    unsigned short* __restrict__ qo,
    unsigned short* __restrict__ Kp,
    unsigned short* __restrict__ Vp)
{
    int bid = blockIdx.x;
    int rt = bid & 127, ct = bid >> 7;
    int row0 = rt * 64;
    int b = row0 >> 11, t0 = row0 & (TT - 1);
    int tid = threadIdx.x;
    int wave = tid >> 6, lane = tid & 63;
    int mrow = lane & 15, quad = lane >> 4;

    __shared__ unsigned short Bs[2][8192];

    f32x4 acc[8];
    #pragma unroll
    for (int ns = 0; ns < 8; ++ns)
        #pragma unroll
        for (int r = 0; r < 4; ++r) acc[ns][r] = 0.f;

    const float* xrow = x + (size_t)(row0 + wave * 16 + mrow) * DD;

    {
        const unsigned short* wt = Wbp + (size_t)(ct * 16) * 8192;
        #pragma unroll
        for (int u = 0; u < 4; ++u)
            gll16(wt + (size_t)(u * 256 + tid) * 8, &Bs[0][(u * 256 + (tid & 192)) * 8]);
    }

    for (int kk = 0; kk < 16; ++kk) {
        __syncthreads();
        if (kk < 15) {
            const unsigned short* wt = Wbp + (size_t)(ct * 16 + kk + 1) * 8192;
            #pragma unroll
            for (int u = 0; u < 4; ++u)
                gll16(wt + (size_t)(u * 256 + tid) * 8, &Bs[(kk + 1) & 1][(u * 256 + (tid & 192)) * 8]);
        }
        bf16x8 af[2];
        #pragma unroll
        for (int kc = 0; kc < 2; ++kc) {
            const float* s = xrow + kk * 64 + kc * 32 + quad * 8;
            float4 f0 = ((const float4*)s)[0];
            float4 f1 = ((const float4*)s)[1];
            bf16x8 pk;
            pk[0]=(short)f2bf(f0.x); pk[1]=(short)f2bf(f0.y); pk[2]=(short)f2bf(f0.z); pk[3]=(short)f2bf(f0.w);
            pk[4]=(short)f2bf(f1.x); pk[5]=(short)f2bf(f1.y); pk[6]=(short)f2bf(f1.z); pk[7]=(short)f2bf(f1.w);
            af[kc] = pk;
        }
        const unsigned short* Bcur = Bs[kk & 1];
        #pragma unroll
        for (int kc = 0; kc < 2; ++kc)
            #pragma unroll
            for (int ns = 0; ns < 8; ++ns) {
                bf16x8 bb = *(const bf16x8*)(Bcur + ((ns * 2 + kc) * 64 + lane) * 8);
                acc[ns] = __builtin_amdgcn_mfma_f32_16x16x32_bf16(af[kc], bb, acc[ns], 0, 0, 0);
            }
    }

    __syncthreads();   // all waves done with Bs; safe to reuse for assembly

    if (ct < 2) {
        unsigned short* dst = qo + (size_t)(b * 2 + ct) * TT * HSZ;
        #pragma unroll
        for (int ns = 0; ns < 8; ++ns) {
            int colloc = ns * 16 + mrow;
            int pj = colloc >> 1;
            #pragma unroll
            for (int r = 0; r < 4; ++r) {
                int t = t0 + wave * 16 + quad * 4 + r;
                float v = acc[ns][r];
                float vp = __shfl_xor(v, 1, 64);
                float2 cs = tab[t * 64 + pj];
                float outv = ((mrow & 1) == 0) ? (v * cs.x - vp * cs.y)
                                               : (v * cs.x + vp * cs.y);
                dst[(size_t)t * HSZ + colloc] = f2bf(outv);
            }
        }
    } else if (ct == 2) {
        // K with RoPE -> K' frag-linear tile
        unsigned short* A_ = (unsigned short*)Bs;
        #pragma unroll
        for (int ns = 0; ns < 8; ++ns) {
            int colloc = ns * 16 + mrow;
            int pj = colloc >> 1;
            int chunk = (ns >> 1) * 4 + wave;
            int lph = (ns & 1) * 2 + (mrow >> 3);
            #pragma unroll
            for (int r = 0; r < 4; ++r) {
                int t = t0 + wave * 16 + quad * 4 + r;
                float v = acc[ns][r];
                float vp = __shfl_xor(v, 1, 64);
                float2 cs = tab[t * 64 + pj];
                float outv = ((mrow & 1) == 0) ? (v * cs.x - vp * cs.y)
                                               : (v * cs.x + vp * cs.y);
                A_[chunk * 512 + (lph * 16 + quad * 4 + r) * 8 + (mrow & 7)] = f2bf(outv);
            }
        }
        __syncthreads();
        unsigned short* kd = Kp + (size_t)(b * 32 + (t0 >> 6)) * 8192;
        #pragma unroll
        for (int u = 0; u < 4; ++u)   // FIX: full 1024-chunk tile (was u<2 = half)
            *(uint4*)(kd + (u * 256 + tid) * 8) = *(const uint4*)(A_ + (u * 256 + tid) * 8);
    } else {
        // V -> V' frag-linear tile
        unsigned short* A_ = (unsigned short*)Bs;
        #pragma unroll
        for (int ns = 0; ns < 8; ++ns) {
            int chunk = ns * 2 + (wave >> 1);
            int lanep = ((wave & 1) * 2 + (quad >> 1)) * 16 + mrow;
            #pragma unroll
            for (int r = 0; r < 4; ++r)
                A_[chunk * 512 + lanep * 8 + (quad & 1) * 4 + r] = f2bf(acc[ns][r]);
        }
        __syncthreads();
        unsigned short* vd = Vp + (size_t)(b * 32 + (t0 >> 6)) * 8192;
        #pragma unroll
        for (int u = 0; u < 4; ++u)   // FIX: full tile (was u<2 = half)
            *(uint4*)(vd + (u * 256 + tid) * 8) = *(const uint4*)(A_ + (u * 256 + tid) * 8);
    }
}

// ---------------- k2: MFMA flash attention, global_load_lds staging ----------------
__global__ __launch_bounds__(256) void attn_mfma_kernel(
    const unsigned short* __restrict__ q,
    const unsigned short* __restrict__ Kp,
    const unsigned short* __restrict__ Vp,
    unsigned short* __restrict__ att)
{
    int bid = blockIdx.x;
    int rr = bid >> 3;
    int qt = (rr < 32) ? rr : 63 - (rr - 32);
    int bh = bid & 7;
    int b = bh >> 1, h = bh & 1;
    int q0 = qt * 32;
    int tid = threadIdx.x;
    int wave = tid >> 6, lane = tid & 63;
    int qsub = wave >> 1, par = wave & 1;
    int qw0 = q0 + qsub * 16;
    int mrow = lane & 15, quad = lane >> 4;

    __shared__ char raw[74240];
    unsigned short* Ks0 = (unsigned short*)raw;            // [2][8192]
    unsigned short* Vs0 = (unsigned short*)(raw + 32768);  // [2][8192]
    unsigned short* Psb = (unsigned short*)(raw + 65536);  // [4][1024]
    float* Ms_ = (float*)(raw + 73728);
    float* Ls_ = Ms_ + 32;
    float* Os  = (float*)raw;

    const unsigned short* qrow = q + (((size_t)(b * 2 + h)) * TT + qw0 + mrow) * HSZ + quad * 8;
    bf16x8 qf[4];
    #pragma unroll
    for (int c = 0; c < 4; ++c) qf[c] = *(const bf16x8*)(qrow + 32 * c);

    float mrun[4], lrun[4];
    f32x4 O[8];
    #pragma unroll
    for (int r = 0; r < 4; ++r) { mrun[r] = -1e30f; lrun[r] = 0.f; }
    #pragma unroll
    for (int g = 0; g < 8; ++g)
        #pragma unroll
        for (int r = 0; r < 4; ++r) O[g][r] = 0.f;

    const int NT = (qt + 2) >> 1;
    const float scl = 0.08838834764831845f;

    for (int jj = 0; jj < NT; jj += 2) {
        __syncthreads();
        for (int tp = 0; tp < 2; ++tp) {
            int j = jj + tp;
            if (j >= NT) break;
            const unsigned short* ks = Kp + (size_t)(b * 32 + j) * 8192;
            const unsigned short* vs = Vp + (size_t)(b * 32 + j) * 8192;
            #pragma unroll
            for (int u = 0; u < 4; ++u) {
                gll16(ks + (size_t)(u * 256 + tid) * 8, Ks0 + (tp * 8192) + (u * 256 + (tid & 192)) * 8);
                gll16(vs + (size_t)(u * 256 + tid) * 8, Vs0 + (tp * 8192) + (u * 256 + (tid & 192)) * 8);
            }
        }
        __syncthreads();

        int j = jj + par;
        int s0 = j * 64;
        if (j < NT && s0 <= qw0 + 15) {
            const unsigned short* Kt = Ks0 + par * 8192;
            const unsigned short* Vtt = Vs0 + par * 8192;

            f32x4 S[4];
            #pragma unroll
            for (int f = 0; f < 4; ++f)
                #pragma unroll
                for (int r = 0; r < 4; ++r) S[f][r] = 0.f;

            #pragma unroll
            for (int c = 0; c < 4; ++c)
                #pragma unroll
                for (int f = 0; f < 4; ++f) {
                    bf16x8 bk = *(const bf16x8*)(Kt + ((c * 4 + f) * 64 + lane) * 8);
                    S[f] = __builtin_amdgcn_mfma_f32_16x16x32_bf16(qf[c], bk, S[f], 0, 0, 0);
                }

            #pragma unroll
            for (int f = 0; f < 4; ++f) {
                int sg = s0 + 16 * f + mrow;
                #pragma unroll
                for (int r = 0; r < 4; ++r) {
                    int qg = qw0 + quad * 4 + r;
                    float val = S[f][r] * scl;
                    S[f][r] = (sg <= qg) ? val : -1e30f;
                }
            }

            float al[4];
            #pragma unroll
            for (int r = 0; r < 4; ++r) {
                float v = fmaxf(fmaxf(S[0][r], S[1][r]), fmaxf(S[2][r], S[3][r]));
                v = fmaxf(v, __shfl_xor(v, 1, 64));
                v = fmaxf(v, __shfl_xor(v, 2, 64));
                v = fmaxf(v, __shfl_xor(v, 4, 64));
                v = fmaxf(v, __shfl_xor(v, 8, 64));
                float mn = fmaxf(mrun[r], v);
                al[r] = __expf(mrun[r] - mn);
                mrun[r] = mn;
            }
            #pragma unroll
            for (int f = 0; f < 4; ++f)
                #pragma unroll
                for (int r = 0; r < 4; ++r)
                    S[f][r] = __expf(S[f][r] - mrun[r]);
            #pragma unroll
            for (int r = 0; r < 4; ++r) {
                float v = (S[0][r] + S[1][r]) + (S[2][r] + S[3][r]);
                v += __shfl_xor(v, 1, 64);
                v += __shfl_xor(v, 2, 64);
                v += __shfl_xor(v, 4, 64);
                v += __shfl_xor(v, 8, 64);
                lrun[r] = lrun[r] * al[r] + v;
            }
            #pragma unroll
            for (int g = 0; g < 8; ++g) {
                O[g][0] *= al[0]; O[g][1] *= al[1]; O[g][2] *= al[2]; O[g][3] *= al[3];
            }

            unsigned short* Pw = Psb + wave * 1024;
            #pragma unroll
            for (int f = 0; f < 4; ++f) {
                int p = f >> 1;
                int hi2 = (2 * f + (mrow >> 3)) & 3;
                int jlo = mrow & 7;
                #pragma unroll
                for (int r = 0; r < 4; ++r)
                    Pw[(p * 64 + hi2 * 16 + quad * 4 + r) * 8 + jlo] = f2bf(S[f][r]);
            }
            bf16x8 pa[2];
            pa[0] = *(const bf16x8*)(Pw + lane * 8);
            pa[1] = *(const bf16x8*)(Pw + (64 + lane) * 8);

            #pragma unroll
            for (int g = 0; g < 8; ++g)
                #pragma unroll
                for (int p = 0; p < 2; ++p) {
                    bf16x8 bv = *(const bf16x8*)(Vtt + ((g * 2 + p) * 64 + lane) * 8);
                    O[g] = __builtin_amdgcn_mfma_f32_16x16x32_bf16(pa[p], bv, O[g], 0, 0, 0);
                }
        }
    }

    __syncthreads();
    if (par == 1) {
        if (mrow == 0) {
            #pragma unroll
            for (int r = 0; r < 4; ++r) {
                Ms_[qsub * 16 + quad * 4 + r] = mrun[r];
                Ls_[qsub * 16 + quad * 4 + r] = lrun[r];
            }
        }
        float* Ow = Os + qsub * 2048;
        #pragma unroll
        for (int g = 0; g < 8; ++g)
            #pragma unroll
            for (int r = 0; r < 4; ++r)
                Ow[(quad * 4 + r) * 128 + g * 16 + mrow] = O[g][r];
    }
    __syncthreads();
    if (par == 0) {
        const float* Op = Os + qsub * 2048;
        float A0[4], A1[4], inv[4];
        #pragma unroll
        for (int r = 0; r < 4; ++r) {
            float m1 = Ms_[qsub * 16 + quad * 4 + r];
            float l1 = Ls_[qsub * 16 + quad * 4 + r];
            float m12 = fmaxf(mrun[r], m1);
            A0[r] = __expf(mrun[r] - m12);
            A1[r] = __expf(m1 - m12);
            inv[r] = 1.f / (lrun[r] * A0[r] + l1 * A1[r]);
        }
        unsigned short* ab = att + (((size_t)b * TT + qw0) * 2 + h) * 128;
        #pragma unroll
        for (int g = 0; g < 8; ++g)
            #pragma unroll
            for (int r = 0; r < 4; ++r) {
                int row = quad * 4 + r;
                float o = (O[g][r] * A0[r] + Op[row * 128 + g * 16 + mrow] * A1[r]) * inv[r];
                ab[(size_t)row * 256 + g * 16 + mrow] = f2bf(o);
            }
    }
}

// ---------------- k3: outproj GEMM, A direct-frag from att, B via global_load_lds ----
__global__ __launch_bounds__(256) void outproj_gemm_kernel(
    const unsigned short* __restrict__ attb,
    const unsigned short* __restrict__ Wop,
    float* __restrict__ y)
{
    int bid = blockIdx.x;
    int rt = bid & 127, ct = bid >> 7;
    int row0 = rt * 64;
    int tid = threadIdx.x;
    int wave = tid >> 6, lane = tid & 63;
    int mrow = lane & 15, quad = lane >> 4;

    __shared__ unsigned short Bs[2][8192];

    f32x4 acc[8];
    #pragma unroll
    for (int ns = 0; ns < 8; ++ns)
        #pragma unroll
        for (int r = 0; r < 4; ++r) acc[ns][r] = 0.f;

    const unsigned short* arow = attb + (size_t)(row0 + wave * 16 + mrow) * 256;

    {
        const unsigned short* wt = Wop + (size_t)(ct * 4) * 8192;
        #pragma unroll
        for (int u = 0; u < 4; ++u)
            gll16(wt + (size_t)(u * 256 + tid) * 8, &Bs[0][(u * 256 + (tid & 192)) * 8]);
    }

    for (int kk = 0; kk < 4; ++kk) {
        __syncthreads();
        if (kk < 3) {
            const unsigned short* wt = Wop + (size_t)(ct * 4 + kk + 1) * 8192;
            #pragma unroll
            for (int u = 0; u < 4; ++u)
                gll16(wt + (size_t)(u * 256 + tid) * 8, &Bs[(kk + 1) & 1][(u * 256 + (tid & 192)) * 8]);
        }
        const unsigned short* Bcur = Bs[kk & 1];
        #pragma unroll
        for (int kc = 0; kc < 2; ++kc) {
            bf16x8 af = *(const bf16x8*)(arow + kk * 64 + kc * 32 + quad * 8);
            #pragma unroll
            for (int ns = 0; ns < 8; ++ns) {
                bf16x8 bb = *(const bf16x8*)(Bcur + ((ns * 2 + kc) * 64 + lane) * 8);
                acc[ns] = __builtin_amdgcn_mfma_f32_16x16x32_bf16(af, bb, acc[ns], 0, 0, 0);
            }
        }
    }

    #pragma unroll
    for (int ns = 0; ns < 8; ++ns)
        #pragma unroll
        for (int r = 0; r < 4; ++r) {
            int row = row0 + wave * 16 + quad * 4 + r;
            y[(size_t)row * DD + ct * 128 + ns * 16 + mrow] = acc[ns][r];
        }
}

extern "C" void kernel_launch(void* const* d_in, const int* in_sizes, int n_in,
                              void* d_out, int out_size, void* d_ws, size_t ws_size,
                              hipStream_t stream) {
    const float* x  = (const float*)d_in[0];
    const float* Wq = (const float*)d_in[1];
    const float* Wk = (const float*)d_in[2];
    const float* Wv = (const float*)d_in[3];
    const float* Wo = (const float*)d_in[4];
    float* y = (float*)d_out;

    // ws: att 4MB | qo 4MB | K' 2MB | V' 2MB | Wb' 1MB | Wo' 0.5MB | tab 1MB  (14.5MB)
    char* ws = (char*)d_ws;
    unsigned short* at  = (unsigned short*)(ws);
    unsigned short* qo  = (unsigned short*)(ws + 4u  * 1024 * 1024);
    unsigned short* Kp  = (unsigned short*)(ws + 8u  * 1024 * 1024);
    unsigned short* Vp  = (unsigned short*)(ws + 10u * 1024 * 1024);
    unsigned short* Wbp = (unsigned short*)(ws + 12u * 1024 * 1024);
    unsigned short* Wop = (unsigned short*)(ws + 13u * 1024 * 1024);
    float2*         tb  = (float2*)        (ws + 13824u * 1024);

    prep_kernel<<<896, 256, 0, stream>>>(Wq, Wk, Wv, Wo, Wbp, Wop, tb);
    qkv_gemm_kernel<<<512, 256, 0, stream>>>(x, Wbp, tb, qo, Kp, Vp);
    attn_mfma_kernel<<<512, 256, 0, stream>>>(qo, Kp, Vp, at);
    outproj_gemm_kernel<<<1024, 256, 0, stream>>>(at, Wop, y);
}